// Round 11
// baseline (304.899 us; speedup 1.0000x reference)
//
#include <hip/hip_runtime.h>
#include <math.h>

#define NEG_SLOPE 0.2f
#define LOG2E 1.4426950408889634f

typedef __attribute__((ext_vector_type(2))) _Float16 h2;
typedef __attribute__((ext_vector_type(4))) _Float16 h4;
typedef __attribute__((ext_vector_type(8))) _Float16 f16x8;
typedef __attribute__((ext_vector_type(4))) float f32x4;

typedef const __attribute__((address_space(1))) unsigned int* gu32p;
typedef __attribute__((address_space(3))) unsigned int* lu32p;

#define GLD16(g, l) __builtin_amdgcn_global_load_lds((gu32p)(g), (lu32p)(l), 16, 0, 0)

template<int CTRL>
__device__ __forceinline__ float dpp_add_f32(float x) {
    int y = __builtin_amdgcn_update_dpp(0, __float_as_int(x), CTRL, 0xF, 0xF, true);
    return x + __int_as_float(y);
}
__device__ __forceinline__ float rowsum16(float x) {
    x = dpp_add_f32<0xB1>(x);
    x = dpp_add_f32<0x4E>(x);
    x = dpp_add_f32<0x124>(x);
    x = dpp_add_f32<0x128>(x);
    return x;
}

// ---------------- CSR build ----------------

__global__ __launch_bounds__(256) void k_scan_block(const int* __restrict__ cnt,
                                                    int* __restrict__ out,
                                                    int* __restrict__ bsums, int n) {
    __shared__ int tmp[256];
    int t = threadIdx.x;
    int i = blockIdx.x * 256 + t;
    int v = (i < n) ? cnt[i] : 0;
    tmp[t] = v;
    __syncthreads();
    for (int d = 1; d < 256; d <<= 1) {
        int add = (t >= d) ? tmp[t - d] : 0;
        __syncthreads();
        tmp[t] += add;
        __syncthreads();
    }
    if (i < n) out[i] = tmp[t] - v;
    if (t == 255) bsums[blockIdx.x] = tmp[t];
}

// absorbs the bsums scan (nb <= 256) — one fewer launch (R13, kept: measured win).
__global__ __launch_bounds__(256) void k_scan_add(int* __restrict__ out,
                                                  const int* __restrict__ bsums,
                                                  int n, int total, int nb) {
    __shared__ int tmp[256];
    int t = threadIdx.x;
    int v = (t < nb) ? bsums[t] : 0;
    tmp[t] = v;
    __syncthreads();
    for (int d = 1; d < 256; d <<= 1) {
        int add = (t >= d) ? tmp[t - d] : 0;
        __syncthreads();
        tmp[t] += add;
        __syncthreads();
    }
    int boff = tmp[blockIdx.x] - bsums[blockIdx.x];   // exclusive prefix of block sums
    int i = blockIdx.x * 256 + t;
    if (i < n) out[i] += boff;
    if (i == 0) out[n] = total;
}

// ---------------- fused prep: edge count+rank + x cast + all weight casts ----------------
// R16 (kept): the counting atomicAdd's return value IS the in-bucket rank.
// R20 (kept): casts vectorized 8 elements/thread (16B f16x8 writes).

__global__ __launch_bounds__(256) void k_prep(
        const int* __restrict__ ei, int E, int Et, int* __restrict__ cnt,
        int* __restrict__ rank,
        const float* __restrict__ x, _Float16* __restrict__ xb, int N, int F,
        const float* __restrict__ Wl1, const float* __restrict__ Wr1,
        const float* __restrict__ Wl2, const float* __restrict__ Wr2,
        const float* __restrict__ Wl3, const float* __restrict__ Wr3,
        _Float16* __restrict__ wtl1, _Float16* __restrict__ wtr1,
        _Float16* __restrict__ wtl2, _Float16* __restrict__ wtr2,
        _Float16* __restrict__ w3t, int gEt, int gX8) {
    const int b = blockIdx.x;
    if (b < gEt) {
        int e = b * 256 + threadIdx.x;
        if (e < Et) {
            int d = (e < E) ? ei[E + e] : (e - E);
            rank[e] = atomicAdd(&cnt[d], 1);
        }
    } else if (b < gEt + gX8) {
        // x cast: 8 channels per thread, 16B writes
        int i = (b - gEt) * 256 + threadIdx.x;
        if (i < (N << 3)) {
            int n = i >> 3, k0 = (i & 7) * 8;
            f16x8 o;
            #pragma unroll
            for (int q = 0; q < 8; q++) {
                int k = k0 + q;
                o[q] = (_Float16)(k < F ? x[n * F + k] : 0.0f);
            }
            *(f16x8*)&xb[(size_t)n * 64 + k0] = o;
        }
    } else {
        // weight transpose-casts: 8 k-elements per thread, 16B writes, strided reads
        int i = (b - gEt - gX8) * 256 + threadIdx.x;
        int j = i * 8;
        if (j < 32768) {
            const float* W = (j < 16384) ? Wl1 : Wr1;
            _Float16* O = (j < 16384) ? wtl1 : wtr1;
            int loc = j & 16383;
            int n = loc >> 6, k0 = loc & 63;
            f16x8 o;
            #pragma unroll
            for (int q = 0; q < 8; q++) {
                int k = k0 + q;
                o[q] = (_Float16)(k < F ? W[k * 256 + n] : 0.0f);
            }
            *(f16x8*)&O[loc] = o;
        } else if (j < 163840) {
            int seg = j - 32768;
            const float* W = (seg < 65536) ? Wl2 : Wr2;
            _Float16* O = (seg < 65536) ? wtl2 : wtr2;
            int loc = seg & 65535;
            int n = loc >> 8, k0 = loc & 255;
            f16x8 o;
            #pragma unroll
            for (int q = 0; q < 8; q++)
                o[q] = (_Float16)W[(k0 + q) * 256 + n];
            *(f16x8*)&O[loc] = o;
        } else if (j < 167936) {
            int loc = j - 163840;
            int jc = loc >> 8, k0 = loc & 255;
            f16x8 o;
            #pragma unroll
            for (int q = 0; q < 8; q++) {
                int k = k0 + q;
                float v = (jc < 6) ? Wl3[k * 6 + jc]
                                   : ((jc < 12) ? Wr3[k * 6 + (jc - 6)] : 0.0f);
                o[q] = (_Float16)v;
            }
            *(f16x8*)&w3t[loc] = o;
        }
    }
}

// ---------------- MFMA fp16 GEMM pair (+ fused atomic-free edge scatter) ----------------
// R17 configuration (measured best). 512-thread blocks, 128 rows x 256 cols per
// block, blockIdx-major mat split. R19's 1024-thread A-share variant was ~10us
// SLOWER: hb fits in L3, so the duplicate A-read was already free. [L3-masking]

__global__ __launch_bounds__(512) void k_gemm_pair_mfma(
        const _Float16* __restrict__ A, int M, int Kp,
        const _Float16* __restrict__ Btl, const _Float16* __restrict__ Btr,
        const float* __restrict__ bl, const float* __restrict__ br,
        _Float16* __restrict__ Cl, _Float16* __restrict__ Cr,
        const int* __restrict__ ei, int E, int Et,
        const int* __restrict__ row_ptr, const int* __restrict__ rank,
        int* __restrict__ src_sorted,
        int sB, int gX) {
    __shared__ _Float16 As[128 * 32];
    __shared__ _Float16 Bs[256 * 32];
    if (blockIdx.x < sB) {
        int e = blockIdx.x * 512 + threadIdx.x;
        if (e < Et) {
            int s, d;
            if (e < E) { s = ei[e]; d = ei[E + e]; } else { s = d = e - E; }
            src_sorted[row_ptr[d] + rank[e]] = s;
        }
        return;
    }
    const int gb = blockIdx.x - sB;
    const int mat = gb >= gX;
    const int bx  = mat ? gb - gX : gb;
    const int tid = threadIdx.x;
    const int wv = tid >> 6, lane = tid & 63;
    const int wr = wv >> 2, wc = wv & 3;
    const int l15 = lane & 15, l4 = lane >> 4;
    const int row0 = bx * 128;
    const _Float16* Bt = mat ? Btr : Btl;
    const float* bias  = mat ? br  : bl;
    _Float16* C        = mat ? Cr  : Cl;

    const int sr = tid >> 2;            // 0..127
    const int sk = (tid & 3) * 8;       // k offset (halves)
    const _Float16* gA  = A  + (size_t)min(row0 + sr, M - 1) * Kp + sk;
    const _Float16* gB0 = Bt + (size_t)sr * Kp + sk;
    const _Float16* gB1 = Bt + (size_t)(sr + 128) * Kp + sk;
    _Float16* lA  = &As[(wv * 16) * 32];            // wave-uniform base
    _Float16* lB0 = &Bs[(wv * 16) * 32];
    _Float16* lB1 = &Bs[(wv * 16 + 128) * 32];

    f32x4 acc[4][4];
    #pragma unroll
    for (int a = 0; a < 4; a++)
        #pragma unroll
        for (int b = 0; b < 4; b++)
            acc[a][b] = (f32x4){0.f, 0.f, 0.f, 0.f};

    for (int k0 = 0; k0 < Kp; k0 += 32) {
        GLD16(gA + k0, lA);
        GLD16(gB0 + k0, lB0);
        GLD16(gB1 + k0, lB1);
        __syncthreads();
        f16x8 wf[4], xf[4];
        #pragma unroll
        for (int ct = 0; ct < 4; ct++)
            wf[ct] = *(const f16x8*)&Bs[(wc * 64 + ct * 16 + l15) * 32 + l4 * 8];
        #pragma unroll
        for (int nt = 0; nt < 4; nt++)
            xf[nt] = *(const f16x8*)&As[(wr * 64 + nt * 16 + l15) * 32 + l4 * 8];
        #pragma unroll
        for (int ct = 0; ct < 4; ct++)
            #pragma unroll
            for (int nt = 0; nt < 4; nt++)
                acc[ct][nt] = __builtin_amdgcn_mfma_f32_16x16x32_f16(
                    wf[ct], xf[nt], acc[ct][nt], 0, 0, 0);
        __syncthreads();
    }

    float4 bv[4];
    #pragma unroll
    for (int ct = 0; ct < 4; ct++)
        bv[ct] = *(const float4*)&bias[wc * 64 + ct * 16 + l4 * 4];
    #pragma unroll
    for (int nt = 0; nt < 4; nt++) {
        int node = row0 + wr * 64 + nt * 16 + l15;
        if (node < M) {
            #pragma unroll
            for (int ct = 0; ct < 4; ct++) {
                h4 hv = {(_Float16)(acc[ct][nt][0] + bv[ct].x),
                         (_Float16)(acc[ct][nt][1] + bv[ct].y),
                         (_Float16)(acc[ct][nt][2] + bv[ct].z),
                         (_Float16)(acc[ct][nt][3] + bv[ct].w)};
                *(h4*)&C[(size_t)node * 256 + wc * 64 + ct * 16 + l4 * 4] = hv;
            }
        }
    }
}

// ---------------- Layer 3 transform via MFMA ----------------

__global__ __launch_bounds__(256) void k_gemm3_mfma(
        const _Float16* __restrict__ h,
        const _Float16* __restrict__ W3t,
        const float* __restrict__ bl, const float* __restrict__ br,
        _Float16* __restrict__ l3, int N) {
    const int wave = threadIdx.x >> 6, lane = threadIdx.x & 63;
    const int l15 = lane & 15, l4 = lane >> 4;
    const int row0 = blockIdx.x * 64 + wave * 16;
    if (row0 >= N) return;

    f16x8 bfr[8];
    #pragma unroll
    for (int ks = 0; ks < 8; ks++)
        bfr[ks] = *(const f16x8*)&W3t[l15 * 256 + ks * 32 + l4 * 8];

    const int arow = min(row0 + l15, N - 1);
    const size_t abase = (size_t)arow * 256;
    f32x4 acc = (f32x4){0.f, 0.f, 0.f, 0.f};
    #pragma unroll
    for (int ks = 0; ks < 8; ks++) {
        f16x8 af = *(const f16x8*)&h[abase + ks * 32 + l4 * 8];
        acc = __builtin_amdgcn_mfma_f32_16x16x32_f16(af, bfr[ks], acc, 0, 0, 0);
    }
    const float bv = (l15 < 6) ? bl[l15] : ((l15 < 12) ? br[l15 - 6] : 0.0f);
    #pragma unroll
    for (int r = 0; r < 4; r++) {
        int gr = row0 + l4 * 4 + r;
        if (gr < N && l15 < 12)
            l3[(size_t)gr * 16 + l15] = (_Float16)(acc[r] + bv);
    }
}

// ---------------- Aggregation layers 1&2 (H=4, C=64), fp16, online softmax ----------------
// Inner per-node dataflow FROZEN (R17: 45.4us/VGPR36 — three restructures regressed).
// R21: persistent grid-stride waves. Old version: 12.5K blocks, 4 waves x 1 node;
// block runtime = max of 4 iid Poisson(10)+1 node-times (~30% wasted wave-slots,
// OccupancyPercent 58%). Now 2048 resident blocks, wave w handles nodes w, w+W, ...
// — per-wave work averages ~6 degree draws (variance /sqrt(6)), no block churn.
// Zero new per-wave state, zero atomics, inner loop byte-identical.

__global__ __launch_bounds__(256) void k_agg256(const _Float16* __restrict__ xl,
                                                const _Float16* __restrict__ xr,
                                                const int* __restrict__ row_ptr,
                                                const int* __restrict__ src_sorted,
                                                const float* __restrict__ att,
                                                const float* __restrict__ bias,
                                                _Float16* __restrict__ h_out, int N) {
    const int wave = threadIdx.x >> 6;
    const int lane = threadIdx.x & 63;
    const int W = gridDim.x * 4;
    const int ci = lane * 4;
    const float4 at4 = *(const float4*)&att[ci];
    const h2 ata = {(_Float16)(at4.x * LOG2E), (_Float16)(at4.y * LOG2E)};
    const h2 atb = {(_Float16)(at4.z * LOG2E), (_Float16)(at4.w * LOG2E)};

    for (int n0 = blockIdx.x * 4 + wave; n0 < N; n0 += W) {
        const int n = __builtin_amdgcn_readfirstlane(n0);
        const h4 xr4 = *(const h4*)&xr[(size_t)n * 256 + ci];
        h4 a4 = {(_Float16)0.f, (_Float16)0.f, (_Float16)0.f, (_Float16)0.f};
        float m = -INFINITY, s = 0.0f;
        const int beg = row_ptr[n], end = row_ptr[n + 1];
        const int rem = (end - beg) & 7;
        const int tb  = end - rem;

        // tail preload — issued before everything else, guarded so no extra traffic
        h4 vt[7];
        #pragma unroll
        for (int e = 0; e < 7; e++) {
            if (e < rem) {
                int sv = src_sorted[tb + e];              // uniform -> s_load
                vt[e] = *(const h4*)&xl[(size_t)sv * 256 + ci];
            }
        }

        int j = beg;
        h4 v[8], vn[8];
        bool has = (j + 8 <= tb);
        if (has) {
            #pragma unroll
            for (int e = 0; e < 8; e++) {
                int sv = src_sorted[j + e];
                v[e] = *(const h4*)&xl[(size_t)sv * 256 + ci];
            }
        }
        while (has) {
            const int jn = j + 8;
            const bool hasN = (jn + 8 <= tb);
            if (hasN) {
                #pragma unroll
                for (int e = 0; e < 8; e++) {
                    int sv = src_sorted[jn + e];
                    vn[e] = *(const h4*)&xl[(size_t)sv * 256 + ci];
                }
            }
            float lg[8];
            #pragma unroll
            for (int e = 0; e < 8; e++) {
                h4 t = v[e] + xr4;
                h4 lk = __builtin_elementwise_max(t, t * (_Float16)NEG_SLOPE);
                h2 lo = __builtin_shufflevector(lk, lk, 0, 1);
                h2 hi = __builtin_shufflevector(lk, lk, 2, 3);
                lg[e] = __builtin_amdgcn_fdot2(lo, ata,
                            __builtin_amdgcn_fdot2(hi, atb, 0.0f, false), false);
            }
            #pragma unroll
            for (int e = 0; e < 8; e++) lg[e] = rowsum16(lg[e]);
            float bm = fmaxf(fmaxf(fmaxf(lg[0], lg[1]), fmaxf(lg[2], lg[3])),
                             fmaxf(fmaxf(lg[4], lg[5]), fmaxf(lg[6], lg[7])));
            float nm = fmaxf(m, bm);
            float sc = __builtin_amdgcn_exp2f(m - nm);
            {
                _Float16 sc16 = (_Float16)sc;
                a4 *= (h4){sc16, sc16, sc16, sc16};
            }
            float ps = 0.f;
            #pragma unroll
            for (int e = 0; e < 8; e++) {
                float p = __builtin_amdgcn_exp2f(lg[e] - nm);
                ps += p;
                _Float16 p16 = (_Float16)p;
                a4 = __builtin_elementwise_fma((h4){p16, p16, p16, p16}, v[e], a4);
            }
            s = s * sc + ps;
            m = nm;
            if (hasN) {
                #pragma unroll
                for (int e = 0; e < 8; e++) v[e] = vn[e];
            }
            j = jn;
            has = hasN;
        }

        // batched tail: rem independent logits, ONE rescale+accumulate pass
        if (rem) {
            float lg[7];
            #pragma unroll
            for (int e = 0; e < 7; e++) {
                if (e < rem) {
                    h4 t = vt[e] + xr4;
                    h4 lk = __builtin_elementwise_max(t, t * (_Float16)NEG_SLOPE);
                    h2 lo = __builtin_shufflevector(lk, lk, 0, 1);
                    h2 hi = __builtin_shufflevector(lk, lk, 2, 3);
                    float d = __builtin_amdgcn_fdot2(lo, ata,
                                  __builtin_amdgcn_fdot2(hi, atb, 0.0f, false), false);
                    lg[e] = rowsum16(d);
                }
            }
            float bm = -INFINITY;
            #pragma unroll
            for (int e = 0; e < 7; e++)
                if (e < rem) bm = fmaxf(bm, lg[e]);
            float nm = fmaxf(m, bm);
            float sc = __builtin_amdgcn_exp2f(m - nm);
            {
                _Float16 sc16 = (_Float16)sc;
                a4 *= (h4){sc16, sc16, sc16, sc16};
            }
            float ps = 0.f;
            #pragma unroll
            for (int e = 0; e < 7; e++) {
                if (e < rem) {
                    float p = __builtin_amdgcn_exp2f(lg[e] - nm);
                    ps += p;
                    _Float16 p16 = (_Float16)p;
                    a4 = __builtin_elementwise_fma((h4){p16, p16, p16, p16}, vt[e], a4);
                }
            }
            s = s * sc + ps;
            m = nm;
        }

        const float inv = 1.0f / s;
        const float4 bv = *(const float4*)&bias[ci];
        float o0 = (float)a4.x * inv + bv.x;
        float o1 = (float)a4.y * inv + bv.y;
        float o2 = (float)a4.z * inv + bv.z;
        float o3 = (float)a4.w * inv + bv.w;
        o0 = o0 > 0.f ? o0 : (__expf(o0) - 1.f);
        o1 = o1 > 0.f ? o1 : (__expf(o1) - 1.f);
        o2 = o2 > 0.f ? o2 : (__expf(o2) - 1.f);
        o3 = o3 > 0.f ? o3 : (__expf(o3) - 1.f);
        h4 hv = {(_Float16)o0, (_Float16)o1, (_Float16)o2, (_Float16)o3};
        *(h4*)&h_out[(size_t)n * 256 + ci] = hv;
    }
}

// ---------------- Layer 3 aggregation (H=6, C=1, mean over heads) ----------------
// R17 version (validated): thread per (node, head), 8x parallelism, shfl_xor mean.

__global__ __launch_bounds__(256) void k_agg3(const _Float16* __restrict__ l3,
                                              const int* __restrict__ row_ptr,
                                              const int* __restrict__ src_sorted,
                                              const float* __restrict__ att3,
                                              const float* __restrict__ bias3,
                                              float* __restrict__ out, int N) {
    const int idx = blockIdx.x * 256 + threadIdx.x;
    const int n = idx >> 3, h = idx & 7;
    if (n >= N) return;                 // uniform per 8-lane group
    float val = 0.0f;
    if (h < 6) {
        const float xrv = (float)l3[(size_t)n * 16 + 6 + h];
        const float attv = att3[h] * LOG2E;
        float m = -INFINITY, s = 0.0f, acc = 0.0f;
        const int beg = row_ptr[n], end = row_ptr[n + 1];
        for (int j = beg; j < end; j += 8) {
            float xlv[8];
            #pragma unroll
            for (int e = 0; e < 8; e++) {
                int i2 = j + e; i2 = i2 < end ? i2 : end - 1;
                int sv = src_sorted[i2];
                xlv[e] = (float)l3[(size_t)sv * 16 + h];
            }
            #pragma unroll
            for (int e = 0; e < 8; e++) {
                const bool valid = (j + e) < end;
                float tt = xlv[e] + xrv;
                float lr = fmaxf(tt, NEG_SLOPE * tt);
                float logit = valid ? (attv * lr) : -INFINITY;
                float nm = fmaxf(m, logit);
                float sc = __builtin_amdgcn_exp2f(m - nm);
                float p  = __builtin_amdgcn_exp2f(logit - nm);
                acc = acc * sc + p * xlv[e];
                s   = s * sc + p;
                m   = nm;
            }
        }
        val = acc / s;
    }
    val += __shfl_xor(val, 1);
    val += __shfl_xor(val, 2);
    val += __shfl_xor(val, 4);
    if (h == 0) out[n] = val * (1.0f / 6.0f) + bias3[0];
}

// ---------------- launch ----------------

extern "C" void kernel_launch(void* const* d_in, const int* in_sizes, int n_in,
                              void* d_out, int out_size, void* d_ws, size_t ws_size,
                              hipStream_t stream) {
    const float* x    = (const float*)d_in[0];
    const int*   ei   = (const int*)  d_in[1];
    const float* Wl1  = (const float*)d_in[2];
    const float* bl1  = (const float*)d_in[3];
    const float* Wr1  = (const float*)d_in[4];
    const float* br1  = (const float*)d_in[5];
    const float* att1 = (const float*)d_in[6];
    const float* bias1= (const float*)d_in[7];
    const float* Wl2  = (const float*)d_in[8];
    const float* bl2  = (const float*)d_in[9];
    const float* Wr2  = (const float*)d_in[10];
    const float* br2  = (const float*)d_in[11];
    const float* att2 = (const float*)d_in[12];
    const float* bias2= (const float*)d_in[13];
    const float* Wl3  = (const float*)d_in[14];
    const float* bl3  = (const float*)d_in[15];
    const float* Wr3  = (const float*)d_in[16];
    const float* br3  = (const float*)d_in[17];
    const float* att3 = (const float*)d_in[18];
    const float* bias3= (const float*)d_in[19];

    const int F  = in_sizes[2] / 256;   // 58
    const int N  = in_sizes[0] / F;     // 50000
    const int E  = in_sizes[1] / 2;     // 500000
    const int Et = E + N;

    char* ws = (char*)d_ws;
    size_t off = 0;
    auto carve = [&](size_t bytes) -> char* {
        char* p = ws + off;
        off = (off + bytes + 255) & ~(size_t)255;
        return p;
    };
    _Float16* xb   = (_Float16*)carve((size_t)N * 64 * 2);
    _Float16* xlb  = (_Float16*)carve((size_t)N * 256 * 2);
    _Float16* xrb  = (_Float16*)carve((size_t)N * 256 * 2);
    _Float16* hb   = (_Float16*)carve((size_t)N * 256 * 2);
    _Float16* wtl1 = (_Float16*)carve(256 * 64 * 2);
    _Float16* wtr1 = (_Float16*)carve(256 * 64 * 2);
    _Float16* wtl2 = (_Float16*)carve(256 * 256 * 2);
    _Float16* wtr2 = (_Float16*)carve(256 * 256 * 2);
    _Float16* w3t  = (_Float16*)carve(16 * 256 * 2);
    _Float16* l3   = (_Float16*)carve((size_t)N * 16 * 2);
    int* cnt        = (int*)carve((size_t)N * 4);
    int* row_ptr    = (int*)carve((size_t)(N + 1) * 4);
    int* rank       = (int*)carve((size_t)Et * 4);
    int* src_sorted = (int*)carve((size_t)Et * 4);
    int* bsums      = (int*)carve(1024 * 4);

    const int gN  = (N + 255) / 256;
    const int gEt = (Et + 255) / 256;
    const int gX8 = ((N << 3) + 255) / 256;   // x-cast, 8 elems/thread
    const int gW8 = (167936 / 8 + 255) / 256; // weight casts, 8 elems/thread
    const int gAgg = 2048;                    // persistent agg blocks (grid-stride)
    const int gx1 = (N + 127) / 128;          // gemm row-blocks
    const int sB  = (Et + 511) / 512;         // scatter blocks (512 threads)

    // --- fused prep (count+rank + casts) after zeroing cnt ---
    hipMemsetAsync(cnt, 0, (size_t)N * 4, stream);
    k_prep<<<gEt + gX8 + gW8, 256, 0, stream>>>(ei, E, Et, cnt, rank, x, xb, N, F,
                                                Wl1, Wr1, Wl2, Wr2, Wl3, Wr3,
                                                wtl1, wtr1, wtl2, wtr2, w3t, gEt, gX8);

    // --- CSR scan ---
    k_scan_block<<<gN, 256, 0, stream>>>(cnt, row_ptr, bsums, N);
    k_scan_add<<<gN, 256, 0, stream>>>(row_ptr, bsums, N, Et, gN);

    // --- Layer 1 (atomic-free scatter fused: blocks [0,sB) scatter) ---
    k_gemm_pair_mfma<<<sB + 2 * gx1, 512, 0, stream>>>(
        xb, N, 64, wtl1, wtr1, bl1, br1, xlb, xrb,
        ei, E, Et, row_ptr, rank, src_sorted, sB, gx1);
    k_agg256<<<gAgg, 256, 0, stream>>>(xlb, xrb, row_ptr, src_sorted, att1, bias1, hb, N);

    // --- Layer 2 ---
    k_gemm_pair_mfma<<<2 * gx1, 512, 0, stream>>>(
        hb, N, 256, wtl2, wtr2, bl2, br2, xlb, xrb,
        ei, E, Et, row_ptr, rank, src_sorted, 0, gx1);
    k_agg256<<<gAgg, 256, 0, stream>>>(xlb, xrb, row_ptr, src_sorted, att2, bias2, hb, N);

    // --- Layer 3 ---
    k_gemm3_mfma<<<(N + 63) / 64, 256, 0, stream>>>(hb, w3t, bl3, br3, l3, N);
    k_agg3<<<((N * 8) + 255) / 256, 256, 0, stream>>>(l3, row_ptr, src_sorted, att3, bias3,
                                                      (float*)d_out, N);
}

// Round 12
// 294.775 us; speedup vs baseline: 1.0343x; 1.0343x over previous
//
#include <hip/hip_runtime.h>
#include <math.h>

#define NEG_SLOPE 0.2f
#define LOG2E 1.4426950408889634f

typedef __attribute__((ext_vector_type(2))) _Float16 h2;
typedef __attribute__((ext_vector_type(4))) _Float16 h4;
typedef __attribute__((ext_vector_type(8))) _Float16 f16x8;
typedef __attribute__((ext_vector_type(4))) float f32x4;

typedef const __attribute__((address_space(1))) unsigned int* gu32p;
typedef __attribute__((address_space(3))) unsigned int* lu32p;

#define GLD16(g, l) __builtin_amdgcn_global_load_lds((gu32p)(g), (lu32p)(l), 16, 0, 0)

template<int CTRL>
__device__ __forceinline__ float dpp_add_f32(float x) {
    int y = __builtin_amdgcn_update_dpp(0, __float_as_int(x), CTRL, 0xF, 0xF, true);
    return x + __int_as_float(y);
}
__device__ __forceinline__ float rowsum16(float x) {
    x = dpp_add_f32<0xB1>(x);
    x = dpp_add_f32<0x4E>(x);
    x = dpp_add_f32<0x124>(x);
    x = dpp_add_f32<0x128>(x);
    return x;
}

// ---------------- CSR build ----------------

__global__ __launch_bounds__(256) void k_scan_block(const int* __restrict__ cnt,
                                                    int* __restrict__ out,
                                                    int* __restrict__ bsums, int n) {
    __shared__ int tmp[256];
    int t = threadIdx.x;
    int i = blockIdx.x * 256 + t;
    int v = (i < n) ? cnt[i] : 0;
    tmp[t] = v;
    __syncthreads();
    for (int d = 1; d < 256; d <<= 1) {
        int add = (t >= d) ? tmp[t - d] : 0;
        __syncthreads();
        tmp[t] += add;
        __syncthreads();
    }
    if (i < n) out[i] = tmp[t] - v;
    if (t == 255) bsums[blockIdx.x] = tmp[t];
}

// absorbs the bsums scan (nb <= 256) — one fewer launch (R13, kept: measured win).
__global__ __launch_bounds__(256) void k_scan_add(int* __restrict__ out,
                                                  const int* __restrict__ bsums,
                                                  int n, int total, int nb) {
    __shared__ int tmp[256];
    int t = threadIdx.x;
    int v = (t < nb) ? bsums[t] : 0;
    tmp[t] = v;
    __syncthreads();
    for (int d = 1; d < 256; d <<= 1) {
        int add = (t >= d) ? tmp[t - d] : 0;
        __syncthreads();
        tmp[t] += add;
        __syncthreads();
    }
    int boff = tmp[blockIdx.x] - bsums[blockIdx.x];   // exclusive prefix of block sums
    int i = blockIdx.x * 256 + t;
    if (i < n) out[i] += boff;
    if (i == 0) out[n] = total;
}

// ---------------- fused prep: edge count+rank + x cast + all weight casts ----------------
// R16 (kept): the counting atomicAdd's return value IS the in-bucket rank.
// R20 (kept): casts vectorized 8 elements/thread (16B f16x8 writes).

__global__ __launch_bounds__(256) void k_prep(
        const int* __restrict__ ei, int E, int Et, int* __restrict__ cnt,
        int* __restrict__ rank,
        const float* __restrict__ x, _Float16* __restrict__ xb, int N, int F,
        const float* __restrict__ Wl1, const float* __restrict__ Wr1,
        const float* __restrict__ Wl2, const float* __restrict__ Wr2,
        const float* __restrict__ Wl3, const float* __restrict__ Wr3,
        _Float16* __restrict__ wtl1, _Float16* __restrict__ wtr1,
        _Float16* __restrict__ wtl2, _Float16* __restrict__ wtr2,
        _Float16* __restrict__ w3t, int gEt, int gX8) {
    const int b = blockIdx.x;
    if (b < gEt) {
        int e = b * 256 + threadIdx.x;
        if (e < Et) {
            int d = (e < E) ? ei[E + e] : (e - E);
            rank[e] = atomicAdd(&cnt[d], 1);
        }
    } else if (b < gEt + gX8) {
        // x cast: 8 channels per thread, 16B writes
        int i = (b - gEt) * 256 + threadIdx.x;
        if (i < (N << 3)) {
            int n = i >> 3, k0 = (i & 7) * 8;
            f16x8 o;
            #pragma unroll
            for (int q = 0; q < 8; q++) {
                int k = k0 + q;
                o[q] = (_Float16)(k < F ? x[n * F + k] : 0.0f);
            }
            *(f16x8*)&xb[(size_t)n * 64 + k0] = o;
        }
    } else {
        // weight transpose-casts: 8 k-elements per thread, 16B writes, strided reads
        int i = (b - gEt - gX8) * 256 + threadIdx.x;
        int j = i * 8;
        if (j < 32768) {
            const float* W = (j < 16384) ? Wl1 : Wr1;
            _Float16* O = (j < 16384) ? wtl1 : wtr1;
            int loc = j & 16383;
            int n = loc >> 6, k0 = loc & 63;
            f16x8 o;
            #pragma unroll
            for (int q = 0; q < 8; q++) {
                int k = k0 + q;
                o[q] = (_Float16)(k < F ? W[k * 256 + n] : 0.0f);
            }
            *(f16x8*)&O[loc] = o;
        } else if (j < 163840) {
            int seg = j - 32768;
            const float* W = (seg < 65536) ? Wl2 : Wr2;
            _Float16* O = (seg < 65536) ? wtl2 : wtr2;
            int loc = seg & 65535;
            int n = loc >> 8, k0 = loc & 255;
            f16x8 o;
            #pragma unroll
            for (int q = 0; q < 8; q++)
                o[q] = (_Float16)W[(k0 + q) * 256 + n];
            *(f16x8*)&O[loc] = o;
        } else if (j < 167936) {
            int loc = j - 163840;
            int jc = loc >> 8, k0 = loc & 255;
            f16x8 o;
            #pragma unroll
            for (int q = 0; q < 8; q++) {
                int k = k0 + q;
                float v = (jc < 6) ? Wl3[k * 6 + jc]
                                   : ((jc < 12) ? Wr3[k * 6 + (jc - 6)] : 0.0f);
                o[q] = (_Float16)v;
            }
            *(f16x8*)&w3t[loc] = o;
        }
    }
}

// ---------------- MFMA fp16 GEMM pair (+ fused atomic-free edge scatter) ----------------
// R17 configuration (measured best). 512-thread blocks, 128 rows x 256 cols per
// block, blockIdx-major mat split. R19's 1024-thread A-share variant was ~10us
// SLOWER: hb fits in L3, so the duplicate A-read was already free. [L3-masking]

__global__ __launch_bounds__(512) void k_gemm_pair_mfma(
        const _Float16* __restrict__ A, int M, int Kp,
        const _Float16* __restrict__ Btl, const _Float16* __restrict__ Btr,
        const float* __restrict__ bl, const float* __restrict__ br,
        _Float16* __restrict__ Cl, _Float16* __restrict__ Cr,
        const int* __restrict__ ei, int E, int Et,
        const int* __restrict__ row_ptr, const int* __restrict__ rank,
        int* __restrict__ src_sorted,
        int sB, int gX) {
    __shared__ _Float16 As[128 * 32];
    __shared__ _Float16 Bs[256 * 32];
    if (blockIdx.x < sB) {
        int e = blockIdx.x * 512 + threadIdx.x;
        if (e < Et) {
            int s, d;
            if (e < E) { s = ei[e]; d = ei[E + e]; } else { s = d = e - E; }
            src_sorted[row_ptr[d] + rank[e]] = s;
        }
        return;
    }
    const int gb = blockIdx.x - sB;
    const int mat = gb >= gX;
    const int bx  = mat ? gb - gX : gb;
    const int tid = threadIdx.x;
    const int wv = tid >> 6, lane = tid & 63;
    const int wr = wv >> 2, wc = wv & 3;
    const int l15 = lane & 15, l4 = lane >> 4;
    const int row0 = bx * 128;
    const _Float16* Bt = mat ? Btr : Btl;
    const float* bias  = mat ? br  : bl;
    _Float16* C        = mat ? Cr  : Cl;

    const int sr = tid >> 2;            // 0..127
    const int sk = (tid & 3) * 8;       // k offset (halves)
    const _Float16* gA  = A  + (size_t)min(row0 + sr, M - 1) * Kp + sk;
    const _Float16* gB0 = Bt + (size_t)sr * Kp + sk;
    const _Float16* gB1 = Bt + (size_t)(sr + 128) * Kp + sk;
    _Float16* lA  = &As[(wv * 16) * 32];            // wave-uniform base
    _Float16* lB0 = &Bs[(wv * 16) * 32];
    _Float16* lB1 = &Bs[(wv * 16 + 128) * 32];

    f32x4 acc[4][4];
    #pragma unroll
    for (int a = 0; a < 4; a++)
        #pragma unroll
        for (int b = 0; b < 4; b++)
            acc[a][b] = (f32x4){0.f, 0.f, 0.f, 0.f};

    for (int k0 = 0; k0 < Kp; k0 += 32) {
        GLD16(gA + k0, lA);
        GLD16(gB0 + k0, lB0);
        GLD16(gB1 + k0, lB1);
        __syncthreads();
        f16x8 wf[4], xf[4];
        #pragma unroll
        for (int ct = 0; ct < 4; ct++)
            wf[ct] = *(const f16x8*)&Bs[(wc * 64 + ct * 16 + l15) * 32 + l4 * 8];
        #pragma unroll
        for (int nt = 0; nt < 4; nt++)
            xf[nt] = *(const f16x8*)&As[(wr * 64 + nt * 16 + l15) * 32 + l4 * 8];
        #pragma unroll
        for (int ct = 0; ct < 4; ct++)
            #pragma unroll
            for (int nt = 0; nt < 4; nt++)
                acc[ct][nt] = __builtin_amdgcn_mfma_f32_16x16x32_f16(
                    wf[ct], xf[nt], acc[ct][nt], 0, 0, 0);
        __syncthreads();
    }

    float4 bv[4];
    #pragma unroll
    for (int ct = 0; ct < 4; ct++)
        bv[ct] = *(const float4*)&bias[wc * 64 + ct * 16 + l4 * 4];
    #pragma unroll
    for (int nt = 0; nt < 4; nt++) {
        int node = row0 + wr * 64 + nt * 16 + l15;
        if (node < M) {
            #pragma unroll
            for (int ct = 0; ct < 4; ct++) {
                h4 hv = {(_Float16)(acc[ct][nt][0] + bv[ct].x),
                         (_Float16)(acc[ct][nt][1] + bv[ct].y),
                         (_Float16)(acc[ct][nt][2] + bv[ct].z),
                         (_Float16)(acc[ct][nt][3] + bv[ct].w)};
                *(h4*)&C[(size_t)node * 256 + wc * 64 + ct * 16 + l4 * 4] = hv;
            }
        }
    }
}

// ---------------- Aggregation layers 1&2 (H=4, C=64), fp16, online softmax ----------------
// Inner per-node dataflow FROZEN (R17/R20: 45.6us, VGPR 36 — FOUR restructures
// regressed: R11 masked, R14 repack, R18 2-node ILP, R21 persistent grid).
// R22: when w3t != null (layer-2 call), the epilogue computes the layer-3
// transform IN-REGISTER from the wave-resident h-row (12 fdot2-dots + 64-lane
// reduce) and writes l3 (24B/node) INSTEAD of hb (512B/node). Removes the
// entire k_gemm3 dispatch + 25.6MB hb write + 25.6MB hb read. Work-removal,
// not restructure — the frozen inner loop is untouched.

__global__ __launch_bounds__(256) void k_agg256(const _Float16* __restrict__ xl,
                                                const _Float16* __restrict__ xr,
                                                const int* __restrict__ row_ptr,
                                                const int* __restrict__ src_sorted,
                                                const float* __restrict__ att,
                                                const float* __restrict__ bias,
                                                _Float16* __restrict__ h_out, int N,
                                                const _Float16* __restrict__ w3t,
                                                const float* __restrict__ bl3,
                                                const float* __restrict__ br3,
                                                _Float16* __restrict__ l3out) {
    const int wave = threadIdx.x >> 6;
    const int lane = threadIdx.x & 63;
    const int n = __builtin_amdgcn_readfirstlane(blockIdx.x * 4 + wave);
    if (n >= N) return;
    const int ci = lane * 4;
    const h4 xr4 = *(const h4*)&xr[(size_t)n * 256 + ci];
    const float4 at4 = *(const float4*)&att[ci];
    const h2 ata = {(_Float16)(at4.x * LOG2E), (_Float16)(at4.y * LOG2E)};
    const h2 atb = {(_Float16)(at4.z * LOG2E), (_Float16)(at4.w * LOG2E)};
    h4 a4 = {(_Float16)0.f, (_Float16)0.f, (_Float16)0.f, (_Float16)0.f};
    float m = -INFINITY, s = 0.0f;
    const int beg = row_ptr[n], end = row_ptr[n + 1];
    const int rem = (end - beg) & 7;
    const int tb  = end - rem;

    // tail preload — issued before everything else, guarded so no extra traffic
    h4 vt[7];
    #pragma unroll
    for (int e = 0; e < 7; e++) {
        if (e < rem) {
            int sv = src_sorted[tb + e];              // uniform -> s_load
            vt[e] = *(const h4*)&xl[(size_t)sv * 256 + ci];
        }
    }

    int j = beg;
    h4 v[8], vn[8];
    bool has = (j + 8 <= tb);
    if (has) {
        #pragma unroll
        for (int e = 0; e < 8; e++) {
            int sv = src_sorted[j + e];
            v[e] = *(const h4*)&xl[(size_t)sv * 256 + ci];
        }
    }
    while (has) {
        const int jn = j + 8;
        const bool hasN = (jn + 8 <= tb);
        if (hasN) {
            #pragma unroll
            for (int e = 0; e < 8; e++) {
                int sv = src_sorted[jn + e];
                vn[e] = *(const h4*)&xl[(size_t)sv * 256 + ci];
            }
        }
        float lg[8];
        #pragma unroll
        for (int e = 0; e < 8; e++) {
            h4 t = v[e] + xr4;
            h4 lk = __builtin_elementwise_max(t, t * (_Float16)NEG_SLOPE);
            h2 lo = __builtin_shufflevector(lk, lk, 0, 1);
            h2 hi = __builtin_shufflevector(lk, lk, 2, 3);
            lg[e] = __builtin_amdgcn_fdot2(lo, ata,
                        __builtin_amdgcn_fdot2(hi, atb, 0.0f, false), false);
        }
        #pragma unroll
        for (int e = 0; e < 8; e++) lg[e] = rowsum16(lg[e]);
        float bm = fmaxf(fmaxf(fmaxf(lg[0], lg[1]), fmaxf(lg[2], lg[3])),
                         fmaxf(fmaxf(lg[4], lg[5]), fmaxf(lg[6], lg[7])));
        float nm = fmaxf(m, bm);
        float sc = __builtin_amdgcn_exp2f(m - nm);
        {
            _Float16 sc16 = (_Float16)sc;
            a4 *= (h4){sc16, sc16, sc16, sc16};
        }
        float ps = 0.f;
        #pragma unroll
        for (int e = 0; e < 8; e++) {
            float p = __builtin_amdgcn_exp2f(lg[e] - nm);
            ps += p;
            _Float16 p16 = (_Float16)p;
            a4 = __builtin_elementwise_fma((h4){p16, p16, p16, p16}, v[e], a4);
        }
        s = s * sc + ps;
        m = nm;
        if (hasN) {
            #pragma unroll
            for (int e = 0; e < 8; e++) v[e] = vn[e];
        }
        j = jn;
        has = hasN;
    }

    // batched tail: rem independent logits, ONE rescale+accumulate pass
    if (rem) {
        float lg[7];
        #pragma unroll
        for (int e = 0; e < 7; e++) {
            if (e < rem) {
                h4 t = vt[e] + xr4;
                h4 lk = __builtin_elementwise_max(t, t * (_Float16)NEG_SLOPE);
                h2 lo = __builtin_shufflevector(lk, lk, 0, 1);
                h2 hi = __builtin_shufflevector(lk, lk, 2, 3);
                float d = __builtin_amdgcn_fdot2(lo, ata,
                              __builtin_amdgcn_fdot2(hi, atb, 0.0f, false), false);
                lg[e] = rowsum16(d);
            }
        }
        float bm = -INFINITY;
        #pragma unroll
        for (int e = 0; e < 7; e++)
            if (e < rem) bm = fmaxf(bm, lg[e]);
        float nm = fmaxf(m, bm);
        float sc = __builtin_amdgcn_exp2f(m - nm);
        {
            _Float16 sc16 = (_Float16)sc;
            a4 *= (h4){sc16, sc16, sc16, sc16};
        }
        float ps = 0.f;
        #pragma unroll
        for (int e = 0; e < 7; e++) {
            if (e < rem) {
                float p = __builtin_amdgcn_exp2f(lg[e] - nm);
                ps += p;
                _Float16 p16 = (_Float16)p;
                a4 = __builtin_elementwise_fma((h4){p16, p16, p16, p16}, vt[e], a4);
            }
        }
        s = s * sc + ps;
        m = nm;
    }

    const float inv = 1.0f / s;
    const float4 bv = *(const float4*)&bias[ci];
    float o0 = (float)a4.x * inv + bv.x;
    float o1 = (float)a4.y * inv + bv.y;
    float o2 = (float)a4.z * inv + bv.z;
    float o3 = (float)a4.w * inv + bv.w;
    o0 = o0 > 0.f ? o0 : (__expf(o0) - 1.f);
    o1 = o1 > 0.f ? o1 : (__expf(o1) - 1.f);
    o2 = o2 > 0.f ? o2 : (__expf(o2) - 1.f);
    o3 = o3 > 0.f ? o3 : (__expf(o3) - 1.f);
    h4 hv = {(_Float16)o0, (_Float16)o1, (_Float16)o2, (_Float16)o3};

    if (w3t == nullptr) {
        *(h4*)&h_out[(size_t)n * 256 + ci] = hv;
    } else {
        // fused layer-3 transform: l3[n][j] = h . w3t[j] + bias3[j], j = 0..11
        const h2 hlo = {hv.x, hv.y};
        const h2 hhi = {hv.z, hv.w};
        float outv = 0.0f;
        #pragma unroll
        for (int jj = 0; jj < 12; jj++) {
            const h4 w = *(const h4*)&w3t[jj * 256 + ci];
            h2 wlo = __builtin_shufflevector(w, w, 0, 1);
            h2 whi = __builtin_shufflevector(w, w, 2, 3);
            float d = __builtin_amdgcn_fdot2(hlo, wlo,
                          __builtin_amdgcn_fdot2(hhi, whi, 0.0f, false), false);
            d = rowsum16(d);
            d += __shfl_xor(d, 16);
            d += __shfl_xor(d, 32);
            d += (jj < 6) ? bl3[jj] : br3[jj - 6];
            outv = (lane == jj) ? d : outv;       // static unroll, no array
        }
        if (lane < 12) l3out[(size_t)n * 16 + lane] = (_Float16)outv;
    }
}

// ---------------- Layer 3 aggregation (H=6, C=1, mean over heads) ----------------
// R17 version (validated): thread per (node, head), 8x parallelism, shfl_xor mean.

__global__ __launch_bounds__(256) void k_agg3(const _Float16* __restrict__ l3,
                                              const int* __restrict__ row_ptr,
                                              const int* __restrict__ src_sorted,
                                              const float* __restrict__ att3,
                                              const float* __restrict__ bias3,
                                              float* __restrict__ out, int N) {
    const int idx = blockIdx.x * 256 + threadIdx.x;
    const int n = idx >> 3, h = idx & 7;
    if (n >= N) return;                 // uniform per 8-lane group
    float val = 0.0f;
    if (h < 6) {
        const float xrv = (float)l3[(size_t)n * 16 + 6 + h];
        const float attv = att3[h] * LOG2E;
        float m = -INFINITY, s = 0.0f, acc = 0.0f;
        const int beg = row_ptr[n], end = row_ptr[n + 1];
        for (int j = beg; j < end; j += 8) {
            float xlv[8];
            #pragma unroll
            for (int e = 0; e < 8; e++) {
                int i2 = j + e; i2 = i2 < end ? i2 : end - 1;
                int sv = src_sorted[i2];
                xlv[e] = (float)l3[(size_t)sv * 16 + h];
            }
            #pragma unroll
            for (int e = 0; e < 8; e++) {
                const bool valid = (j + e) < end;
                float tt = xlv[e] + xrv;
                float lr = fmaxf(tt, NEG_SLOPE * tt);
                float logit = valid ? (attv * lr) : -INFINITY;
                float nm = fmaxf(m, logit);
                float sc = __builtin_amdgcn_exp2f(m - nm);
                float p  = __builtin_amdgcn_exp2f(logit - nm);
                acc = acc * sc + p * xlv[e];
                s   = s * sc + p;
                m   = nm;
            }
        }
        val = acc / s;
    }
    val += __shfl_xor(val, 1);
    val += __shfl_xor(val, 2);
    val += __shfl_xor(val, 4);
    if (h == 0) out[n] = val * (1.0f / 6.0f) + bias3[0];
}

// ---------------- launch ----------------

extern "C" void kernel_launch(void* const* d_in, const int* in_sizes, int n_in,
                              void* d_out, int out_size, void* d_ws, size_t ws_size,
                              hipStream_t stream) {
    const float* x    = (const float*)d_in[0];
    const int*   ei   = (const int*)  d_in[1];
    const float* Wl1  = (const float*)d_in[2];
    const float* bl1  = (const float*)d_in[3];
    const float* Wr1  = (const float*)d_in[4];
    const float* br1  = (const float*)d_in[5];
    const float* att1 = (const float*)d_in[6];
    const float* bias1= (const float*)d_in[7];
    const float* Wl2  = (const float*)d_in[8];
    const float* bl2  = (const float*)d_in[9];
    const float* Wr2  = (const float*)d_in[10];
    const float* br2  = (const float*)d_in[11];
    const float* att2 = (const float*)d_in[12];
    const float* bias2= (const float*)d_in[13];
    const float* Wl3  = (const float*)d_in[14];
    const float* bl3  = (const float*)d_in[15];
    const float* Wr3  = (const float*)d_in[16];
    const float* br3  = (const float*)d_in[17];
    const float* att3 = (const float*)d_in[18];
    const float* bias3= (const float*)d_in[19];

    const int F  = in_sizes[2] / 256;   // 58
    const int N  = in_sizes[0] / F;     // 50000
    const int E  = in_sizes[1] / 2;     // 500000
    const int Et = E + N;

    char* ws = (char*)d_ws;
    size_t off = 0;
    auto carve = [&](size_t bytes) -> char* {
        char* p = ws + off;
        off = (off + bytes + 255) & ~(size_t)255;
        return p;
    };
    _Float16* xb   = (_Float16*)carve((size_t)N * 64 * 2);
    _Float16* xlb  = (_Float16*)carve((size_t)N * 256 * 2);
    _Float16* xrb  = (_Float16*)carve((size_t)N * 256 * 2);
    _Float16* hb   = (_Float16*)carve((size_t)N * 256 * 2);
    _Float16* wtl1 = (_Float16*)carve(256 * 64 * 2);
    _Float16* wtr1 = (_Float16*)carve(256 * 64 * 2);
    _Float16* wtl2 = (_Float16*)carve(256 * 256 * 2);
    _Float16* wtr2 = (_Float16*)carve(256 * 256 * 2);
    _Float16* w3t  = (_Float16*)carve(16 * 256 * 2);
    _Float16* l3   = (_Float16*)carve((size_t)N * 16 * 2);
    int* cnt        = (int*)carve((size_t)N * 4);
    int* row_ptr    = (int*)carve((size_t)(N + 1) * 4);
    int* rank       = (int*)carve((size_t)Et * 4);
    int* src_sorted = (int*)carve((size_t)Et * 4);
    int* bsums      = (int*)carve(1024 * 4);

    const int gN  = (N + 255) / 256;
    const int gEt = (Et + 255) / 256;
    const int gX8 = ((N << 3) + 255) / 256;   // x-cast, 8 elems/thread
    const int gW8 = (167936 / 8 + 255) / 256; // weight casts, 8 elems/thread
    const int gW  = (N + 3) / 4;
    const int gx1 = (N + 127) / 128;          // gemm row-blocks
    const int sB  = (Et + 511) / 512;         // scatter blocks (512 threads)

    // --- fused prep (count+rank + casts) after zeroing cnt ---
    hipMemsetAsync(cnt, 0, (size_t)N * 4, stream);
    k_prep<<<gEt + gX8 + gW8, 256, 0, stream>>>(ei, E, Et, cnt, rank, x, xb, N, F,
                                                Wl1, Wr1, Wl2, Wr2, Wl3, Wr3,
                                                wtl1, wtr1, wtl2, wtr2, w3t, gEt, gX8);

    // --- CSR scan ---
    k_scan_block<<<gN, 256, 0, stream>>>(cnt, row_ptr, bsums, N);
    k_scan_add<<<gN, 256, 0, stream>>>(row_ptr, bsums, N, Et, gN);

    // --- Layer 1 (atomic-free scatter fused: blocks [0,sB) scatter) ---
    k_gemm_pair_mfma<<<sB + 2 * gx1, 512, 0, stream>>>(
        xb, N, 64, wtl1, wtr1, bl1, br1, xlb, xrb,
        ei, E, Et, row_ptr, rank, src_sorted, sB, gx1);
    k_agg256<<<gW, 256, 0, stream>>>(xlb, xrb, row_ptr, src_sorted, att1, bias1, hb, N,
                                     nullptr, nullptr, nullptr, nullptr);

    // --- Layer 2 (layer-3 transform fused into the agg epilogue; no hb write) ---
    k_gemm_pair_mfma<<<2 * gx1, 512, 0, stream>>>(
        hb, N, 256, wtl2, wtr2, bl2, br2, xlb, xrb,
        ei, E, Et, row_ptr, rank, src_sorted, 0, gx1);
    k_agg256<<<gW, 256, 0, stream>>>(xlb, xrb, row_ptr, src_sorted, att2, bias2, hb, N,
                                     w3t, bl3, br3, l3);

    // --- Layer 3 aggregation ---
    k_agg3<<<((N * 8) + 255) / 256, 256, 0, stream>>>(l3, row_ptr, src_sorted, att3, bias3,
                                                      (float*)d_out, N);
}